// Round 1
// baseline (202.839 us; speedup 1.0000x reference)
//
#include <hip/hip_runtime.h>
#include <math.h>

// ---------------------------------------------------------------------------
// GMM log-likelihood, N=2M x D=16, K=32, out = mean_n logsumexp_k loglik[n,k]
//
// loglik[n,k] = sum_{ij} (-0.5 P_ij) x_i x_j + (P mu)_i x_i + c_k  (log2 dom.)
// LINEAR in phi(x) = [ x_i*x_j (256), x_i (16), 1 ] -> 18 K16-chunks of one
// chained mfma_f32_32x32x16_f16 (M=32 = all comps; c_k folded in as chunk 17).
// C layout (HW-verified): col=lane&31 (point), row=(reg&3)+8*(reg>>2)+4*(lane>>5).
// Lane pair (l, l^32) holds all 32 comps of a point; combined via
// v_permlane32_swap (VALU-only; ds shuffles cost ~62 cyc each, R2).
//
// R7: R6 (pair-per-iter, W-in-regs, __launch_bounds__(256,2)) ran main at
// ~45 us vs the 20.3 us HBM floor (128 MB once). Issue work per SIMD is only
// ~11 us -> latency-bound at 2 waves/SIMD with 1-iter prefetch distance.
// Fix: ONE 32-point tile per iteration halves per-iter register state
// (acc 32->16, prefetch 32->16, xh/xs 24->12): ~140 VGPRs fits the 168 cap
// of __launch_bounds__(256,3) -> 3 waves/SIMD (+50% TLP), grid 768 = exactly
// 3 blocks/CU persistent. Same MFMA/VALU cost per point; only ~10 loop
// instrs/tile duplicated. Spill tell: WRITE_SIZE on main's dispatch.
// ---------------------------------------------------------------------------

#define LOG_2PI 1.8378770664093453f
#define INV_LN2 1.4426950408889634f
#define LN2_D   0.6931471805599453

typedef float    float4v __attribute__((ext_vector_type(4)));
typedef float    f32x16  __attribute__((ext_vector_type(16)));
typedef _Float16 f16x8   __attribute__((ext_vector_type(8)));
typedef _Float16 f16x2   __attribute__((ext_vector_type(2)));

union H8 { f16x8 h8; f16x2 h2[4]; };

#if __has_builtin(__builtin_amdgcn_exp2f)
#define EXP2F(x) __builtin_amdgcn_exp2f(x)
#else
#define EXP2F(x) exp2f(x)
#endif
#if __has_builtin(__builtin_amdgcn_logf)
#define LOG2F(x) __builtin_amdgcn_logf(x)
#else
#define LOG2F(x) log2f(x)
#endif

static __device__ __forceinline__ f16x2 pk2(float a, float b) {
#if __has_builtin(__builtin_amdgcn_cvt_pkrtz)
  return __builtin_bit_cast(f16x2, __builtin_amdgcn_cvt_pkrtz(a, b));
#else
  f16x2 r; r[0] = (_Float16)a; r[1] = (_Float16)b; return r;
#endif
}

// value of x in partner lane (lane ^ 32), VALU-only on gfx950
static __device__ __forceinline__ float partner32(float x, bool lo) {
#if __has_builtin(__builtin_amdgcn_permlane32_swap)
  typedef unsigned u32x2 __attribute__((ext_vector_type(2)));
  unsigned u = __builtin_bit_cast(unsigned, x);
  u32x2 r = __builtin_amdgcn_permlane32_swap(u, u, false, false);
  return __builtin_bit_cast(float, lo ? r[1] : r[0]);
#else
  return __shfl_xor(x, 32, 64);
#endif
}

// dword select (works for f16x2 payloads)
static __device__ __forceinline__ f16x2 sel2(bool c, f16x2 a, f16x2 b) {
  unsigned ua = __builtin_bit_cast(unsigned, a);
  unsigned ub = __builtin_bit_cast(unsigned, b);
  return __builtin_bit_cast(f16x2, c ? ua : ub);
}

// ---------------------------------------------------------------------------
// Setup: per component k: cov = A A^T, Cholesky L, Linv, P = Linv^T Linv.
// W in 32x32x16 A-frag order: lane l holds A[m=l&31][k16 = 8*(l>>5)+v],
// chunk c covers feature k = 16c + 8h + v.
// chunks 0..15: (i,j)=(c, 8h+v) -> -0.5/ln2 * P[i][j]
// chunk 16: linear, feature i=8h+v -> (P mu)_i / ln2
// chunk 17: constant, slot (h=0,v=0) -> c2[m]; all other slots 0
// ---------------------------------------------------------------------------
__global__ void setup_kernel(const float* __restrict__ means,
                             const float* __restrict__ cov_parts,
                             const float* __restrict__ log_weights,
                             _Float16* __restrict__ W)
{
  const int k = blockIdx.x;
  const int i = threadIdx.x;

  __shared__ float sA[16][17];
  __shared__ float sC[16][17];
  __shared__ float sMu[16];
  __shared__ float sR[16];

  if (i < 16) {
    #pragma unroll
    for (int j = 0; j < 16; ++j) sA[i][j] = cov_parts[(k*16 + i)*16 + j];
    sMu[i] = means[k*16 + i];
  }
  __syncthreads();

  if (i < 16) {
    #pragma unroll
    for (int j = 0; j < 16; ++j) {
      float acc = 0.f;
      #pragma unroll
      for (int l = 0; l < 16; ++l) acc += sA[i][l] * sA[j][l];
      sC[i][j] = acc;
    }
  }
  __syncthreads();

  for (int j = 0; j < 16; ++j) {
    if (i == j) {
      float d = sC[j][j];
      for (int l = 0; l < j; ++l) d -= sC[j][l]*sC[j][l];
      sC[j][j] = sqrtf(d);
    }
    __syncthreads();
    if (i < 16 && i > j) {
      float a = sC[i][j];
      for (int l = 0; l < j; ++l) a -= sC[i][l]*sC[j][l];
      sC[i][j] = a / sC[j][j];
    }
    __syncthreads();
  }

  if (i < 16) {
    float y[16];
    #pragma unroll
    for (int r = 0; r < 16; ++r) {
      float a = (r == i) ? 1.f : 0.f;
      #pragma unroll
      for (int l = 0; l < r; ++l) a -= sC[r][l] * y[l];
      y[r] = a / sC[r][r];
    }
    #pragma unroll
    for (int r = 0; r < 16; ++r) sA[r][i] = y[r];
  }
  __syncthreads();

  if (i < 16) {
    float p[16];
    #pragma unroll
    for (int j = 0; j < 16; ++j) {
      float acc = 0.f;
      #pragma unroll
      for (int l = 0; l < 16; ++l) acc += sA[l][i] * sA[l][j];
      p[j] = acc;
    }
    float ri = 0.f;
    #pragma unroll
    for (int j = 0; j < 16; ++j) ri += p[j] * sMu[j];
    sR[i] = ri;

    #pragma unroll
    for (int j = 0; j < 16; ++j) {
      W[(size_t)(i*64 + (k + 32*(j >> 3)))*8 + (j & 7)] =
          (_Float16)(-0.5f * INV_LN2 * p[j]);
    }
    W[(size_t)(16*64 + (k + 32*(i >> 3)))*8 + (i & 7)] =
        (_Float16)(INV_LN2 * ri);
  }
  __syncthreads();

  if (i == 0) {
    float logdet = 0.f;
    #pragma unroll
    for (int j = 0; j < 16; ++j) logdet += __logf(sC[j][j]);
    float mupmu = 0.f;
    #pragma unroll
    for (int j = 0; j < 16; ++j) mupmu += sMu[j] * sR[j];
    float lw = log_weights[k];
    float c2v = INV_LN2 * (-0.5f*(mupmu + 16.f*LOG_2PI) - logdet + lw*lw);
    #pragma unroll
    for (int v = 0; v < 8; ++v) {
      W[(size_t)(17*64 + k)*8 + v]      = (v == 0) ? (_Float16)c2v : (_Float16)0.f;
      W[(size_t)(17*64 + k + 32)*8 + v] = (_Float16)0.f;
    }
  }
}

// ---------------------------------------------------------------------------
__global__ __launch_bounds__(256, 3) void main_kernel(
    const float* __restrict__ data,
    const _Float16* __restrict__ W,
    float* __restrict__ partials,
    int ntiles)
{
  const int lane = threadIdx.x & 63;
  const int n32  = lane & 31;
  const bool lo  = lane < 32;
  const int gwave  = (int)((blockIdx.x * blockDim.x + threadIdx.x) >> 6);
  const int nwaves = (int)((gridDim.x * blockDim.x) >> 6);

  // W fragments resident in registers for the whole kernel (72 regs)
  f16x8 Wf[18];
  #pragma unroll
  for (int c = 0; c < 18; ++c)
    Wf[c] = *(const f16x8*)(W + (size_t)(c*64 + lane)*8);

  // constant B fragment for the c2 chunk: slot (h=0,v=0) = 1
  H8 bC;
  #pragma unroll
  for (int j = 0; j < 4; ++j) bC.h2[j] = pk2(0.f, 0.f);
  if (lo) bC.h2[0] = pk2(1.f, 0.f);

  float accsum = 0.f;

  // tile t covers points [t*32, t*32+32); lane pair (l, l^32) share point n32
  const char* ptr = (const char*)data + ((size_t)gwave*2048 + (size_t)n32*64);
  const size_t step = (size_t)nwaves * 2048;

  float4v p0, p1, p2, p3;
  if (gwave < ntiles) {
    p0 = *(const float4v*)(ptr);      p1 = *(const float4v*)(ptr + 16);
    p2 = *(const float4v*)(ptr + 32); p3 = *(const float4v*)(ptr + 48);
  }

  for (int t = gwave; t < ntiles; t += nwaves) {
    // convert to f16 pairs: xh[q] = (x[2q], x[2q+1])
    f16x2 xh[8];
    xh[0] = pk2(p0[0], p0[1]); xh[1] = pk2(p0[2], p0[3]);
    xh[2] = pk2(p1[0], p1[1]); xh[3] = pk2(p1[2], p1[3]);
    xh[4] = pk2(p2[0], p2[1]); xh[5] = pk2(p2[2], p2[3]);
    xh[6] = pk2(p3[0], p3[1]); xh[7] = pk2(p3[2], p3[3]);

    ptr += step;
    if (t + nwaves < ntiles) {          // wave-uniform prefetch of next tile
      p0 = *(const float4v*)(ptr);      p1 = *(const float4v*)(ptr + 16);
      p2 = *(const float4v*)(ptr + 32); p3 = *(const float4v*)(ptr + 48);
    }

    // second factors for this lane half: xs[j] = xh[4h + j]
    f16x2 xs[4];
    #pragma unroll
    for (int j = 0; j < 4; ++j) xs[j] = sel2(lo, xh[j], xh[4+j]);

    f32x16 acc;
    #pragma unroll
    for (int r = 0; r < 16; ++r) acc[r] = 0.f;

    #pragma unroll
    for (int c = 0; c < 16; ++c) {
      _Float16 xi = xh[c >> 1][c & 1];
      H8 b;
      #pragma unroll
      for (int j = 0; j < 4; ++j) b.h2[j] = xs[j] * xi;  // v_pk_mul_f16
      acc = __builtin_amdgcn_mfma_f32_32x32x16_f16(Wf[c], b.h8, acc, 0, 0, 0);
    }
    {   // linear chunk
      H8 b;
      #pragma unroll
      for (int j = 0; j < 4; ++j) b.h2[j] = xs[j];
      acc = __builtin_amdgcn_mfma_f32_32x32x16_f16(Wf[16], b.h8, acc, 0, 0, 0);
    }
    // c2 chunk
    acc = __builtin_amdgcn_mfma_f32_32x32x16_f16(Wf[17], bC.h8, acc, 0, 0, 0);

    // epilogue: logsumexp (log2 domain), acc already includes c2
    float m = acc[0];
    #pragma unroll
    for (int r = 1; r < 16; ++r) m = fmaxf(m, acc[r]);
    m = fmaxf(m, partner32(m, lo));
    float s = 0.f;
    #pragma unroll
    for (int r = 0; r < 16; ++r) s += EXP2F(acc[r] - m);
    s += partner32(s, lo);
    accsum += m + LOG2F(s);
  }

  #pragma unroll
  for (int off = 1; off <= 32; off <<= 1)
    accsum += __shfl_xor(accsum, off, 64);

  __shared__ float wsum[4];
  const int wid = (int)(threadIdx.x >> 6);
  if ((threadIdx.x & 63) == 0) wsum[wid] = accsum;
  __syncthreads();
  if (threadIdx.x == 0)
    partials[blockIdx.x] = wsum[0] + wsum[1] + wsum[2] + wsum[3];
}

// ---------------------------------------------------------------------------
__global__ void reduce_kernel(const float* __restrict__ partials, int n,
                              float* __restrict__ out, double scale)
{
  __shared__ double sd[256];
  double a = 0.0;
  for (int idx = threadIdx.x; idx < n; idx += 256) a += (double)partials[idx];
  sd[threadIdx.x] = a;
  __syncthreads();
  for (int s = 128; s > 0; s >>= 1) {
    if ((int)threadIdx.x < s) sd[threadIdx.x] += sd[threadIdx.x + s];
    __syncthreads();
  }
  if (threadIdx.x == 0) out[0] = (float)(sd[0] * scale);
}

extern "C" void kernel_launch(void* const* d_in, const int* in_sizes, int n_in,
                              void* d_out, int out_size, void* d_ws, size_t ws_size,
                              hipStream_t stream)
{
  const float* data        = (const float*)d_in[0];
  const float* means       = (const float*)d_in[1];
  const float* cov_parts   = (const float*)d_in[2];
  const float* log_weights = (const float*)d_in[3];

  const int npts   = in_sizes[0] / 16;
  const int ntiles = npts / 32;        // N = 2,000,000 divisible by 32

  _Float16* W      = (_Float16*)d_ws;                          // 18*64*8 halfs
  float*    partials = (float*)((char*)d_ws + (size_t)18*64*8*sizeof(_Float16));

  const int GRID = 768, BLOCK = 256;   // 3 blocks/CU, one resident round
  setup_kernel<<<32, 64, 0, stream>>>(means, cov_parts, log_weights, W);
  main_kernel<<<GRID, BLOCK, 0, stream>>>(data, W, partials, ntiles);
  reduce_kernel<<<1, 256, 0, stream>>>(partials, GRID, (float*)d_out,
                                       LN2_D / (2.0 * (double)npts));
}